// Round 5
// baseline (17484.094 us; speedup 1.0000x reference)
//
#include <hip/hip_runtime.h>

typedef unsigned short u16;
typedef unsigned long long u64;
typedef __attribute__((ext_vector_type(8))) short bf16x8;
typedef __attribute__((ext_vector_type(4))) float f32x4;

#define BSZ 32
#define TT 512
#define GG (BSZ*TT)      // 16384
#define NNODE 64
#define EE 126
#define H8 1024
#define H3 3072
#define NARRIVE 256      // enc_fused waves

__device__ __forceinline__ float b2f(u16 u){
  union { unsigned i; float f; } v; v.i = ((unsigned)u) << 16; return v.f;
}
__device__ __forceinline__ u16 f2b(float f){
  unsigned i = __float_as_uint(f);
  unsigned r = (i + 0x7FFFu + ((i >> 16) & 1u)) >> 16;   // RNE
  return (u16)r;
}
__device__ __forceinline__ float sigm(float x){ return 1.f/(1.f+__expf(-x)); }
__device__ __forceinline__ float tanh_f(float x){
  float xc = fminf(fmaxf(x, -15.f), 15.f);
  float e = __expf(2.f*xc);
  return (e-1.f)/(e+1.f);
}
__device__ __forceinline__ int prow(int m, int perm){
  return perm ? ((m & (TT-1))*BSZ + (m >> 9)) : m;
}
__device__ __forceinline__ u64 aload64(const u64* p){
  return __hip_atomic_load(p, __ATOMIC_RELAXED, __HIP_MEMORY_SCOPE_AGENT);
}

// ---------------- dtype detection: *flag = 1 if inputs are fp32 ----------------
__global__ __launch_bounds__(256) void detect_dtype(const void* xraw, int* flag){
  __shared__ int cnt;
  if (threadIdx.x == 0) cnt = 0;
  __syncthreads();
  const u16* p = (const u16*)xraw;
  u16 u = p[2*threadIdx.x];
  int e = (u >> 7) & 0xFF;
  int weird = (e < 100 || e > 134) ? 1 : 0;
  atomicAdd(&cnt, weird);
  __syncthreads();
  if (threadIdx.x == 0) *flag = (cnt > 128) ? 1 : 0;
}

__global__ __launch_bounds__(256) void cvt_bf16(const void* __restrict__ in,
                                                u16* __restrict__ out, int n,
                                                const int* __restrict__ flag){
  int i = blockIdx.x*256 + threadIdx.x;
  if (i >= n) return;
  if (*flag) out[i] = f2b(((const float*)in)[i]);
  else       out[i] = ((const u16*)in)[i];
}

// ---------------- GCN ----------------
__global__ __launch_bounds__(64) void gcn_kernel(
    const u16* __restrict__ x, const int* __restrict__ ei,
    const u16* __restrict__ w1, const u16* __restrict__ b1,
    const u16* __restrict__ w2, const u16* __restrict__ b2,
    const u16* __restrict__ cw, const u16* __restrict__ cb,
    u16* __restrict__ res)
{
  __shared__ int se[EE], de[EE];
  __shared__ float dinv[NNODE];
  __shared__ float nrm[EE];
  __shared__ float hs[NNODE][4];
  const int n = threadIdx.x;
  const int g = blockIdx.x;
  for (int e = n; e < EE; e += 64){ se[e] = ei[e]; de[e] = ei[EE + e]; }
  __syncthreads();
  int cnt = 0;
  for (int e = 0; e < EE; e++) cnt += (de[e] == n) ? 1 : 0;
  float di = rsqrtf(1.0f + (float)cnt);
  dinv[n] = di;
  float x0 = b2f(x[((size_t)g*NNODE + n)*2 + 0]);
  float x1 = b2f(x[((size_t)g*NNODE + n)*2 + 1]);
  float hw[4];
  #pragma unroll
  for (int c = 0; c < 4; c++) hw[c] = x0*b2f(w1[c]) + x1*b2f(w1[4+c]);
  #pragma unroll
  for (int c = 0; c < 4; c++) hs[n][c] = hw[c];
  __syncthreads();
  for (int e = n; e < EE; e += 64) nrm[e] = dinv[se[e]] * dinv[de[e]];
  __syncthreads();
  float selfc = di*di;
  float agg[4];
  #pragma unroll
  for (int c = 0; c < 4; c++) agg[c] = hw[c]*selfc;
  for (int e = 0; e < EE; e++){
    if (de[e] == n){
      float w = nrm[e]; int s = se[e];
      #pragma unroll
      for (int c = 0; c < 4; c++) agg[c] += hs[s][c]*w;
    }
  }
  float h1[4];
  #pragma unroll
  for (int c = 0; c < 4; c++) h1[c] = tanh_f(agg[c] + b2f(b1[c]));
  __syncthreads();
  float hw2[2];
  #pragma unroll
  for (int c = 0; c < 2; c++){
    float s = 0.f;
    #pragma unroll
    for (int k = 0; k < 4; k++) s += h1[k]*b2f(w2[k*2+c]);
    hw2[c] = s;
    hs[n][c] = s;
  }
  __syncthreads();
  float agg2[2] = { hw2[0]*selfc, hw2[1]*selfc };
  for (int e = 0; e < EE; e++){
    if (de[e] == n){
      float w = nrm[e]; int s = se[e];
      agg2[0] += hs[s][0]*w;
      agg2[1] += hs[s][1]*w;
    }
  }
  float h2a = tanh_f(agg2[0] + b2f(b2[0]));
  float h2b = tanh_f(agg2[1] + b2f(b2[1]));
  #pragma unroll
  for (int c = 0; c < 2; c++){
    float o = h2a*b2f(cw[c]) + h2b*b2f(cw[2+c]) + b2f(cb[c]);
    res[(size_t)g*128 + n*2 + c] = f2b(o);
  }
}

// ---------------- bf16 transpose ----------------
__global__ __launch_bounds__(256) void transpose_bf16(
    const u16* __restrict__ in, u16* __restrict__ out, int R, int C)
{
  __shared__ u16 tile[32][33];
  int c0 = blockIdx.x*32, r0 = blockIdx.y*32;
  for (int i = threadIdx.y; i < 32; i += 8)
    tile[i][threadIdx.x] = in[(size_t)(r0+i)*C + c0 + threadIdx.x];
  __syncthreads();
  for (int i = threadIdx.y; i < 32; i += 8)
    out[(size_t)(c0+i)*R + r0 + threadIdx.x] = tile[threadIdx.x][i];
}

// ---------------- GEMM NT (bf16 out) ----------------
__global__ __launch_bounds__(256) void gemm_nt(
    const u16* __restrict__ A, const u16* __restrict__ Bm,
    const u16* __restrict__ bias, u16* __restrict__ C,
    int M, int N, int K, int relu, int permA, int permC)
{
  const int wave = threadIdx.x >> 6;
  const int lane = threadIdx.x & 63;
  const int wm = wave >> 1, wn = wave & 1;
  const int q = lane >> 4, lr = lane & 15;
  const int mBase = blockIdx.y*128 + wm*64;
  const int nBase = blockIdx.x*128 + wn*64;
  f32x4 acc[4][4] = {};
  const u16* ap[4]; const u16* bp[4];
  #pragma unroll
  for (int i = 0; i < 4; i++){
    ap[i] = A + (size_t)prow(mBase + i*16 + lr, permA)*K + q*8;
    bp[i] = Bm + (size_t)(nBase + i*16 + lr)*K + q*8;
  }
  for (int kb = 0; kb < K; kb += 32){
    bf16x8 av[4], bv[4];
    #pragma unroll
    for (int i = 0; i < 4; i++){
      av[i] = *(const bf16x8*)ap[i]; bv[i] = *(const bf16x8*)bp[i];
      ap[i] += 32; bp[i] += 32;
    }
    #pragma unroll
    for (int mi = 0; mi < 4; mi++)
      #pragma unroll
      for (int ni = 0; ni < 4; ni++)
        acc[mi][ni] = __builtin_amdgcn_mfma_f32_16x16x32_bf16(av[mi], bv[ni], acc[mi][ni], 0, 0, 0);
  }
  #pragma unroll
  for (int ni = 0; ni < 4; ni++){
    int col = nBase + ni*16 + lr;
    float bb = bias ? b2f(bias[col]) : 0.f;
    #pragma unroll
    for (int mi = 0; mi < 4; mi++){
      #pragma unroll
      for (int r = 0; r < 4; r++){
        int row = prow(mBase + mi*16 + q*4 + r, permC);
        float v = acc[mi][ni][r] + bb;
        if (relu) v = fmaxf(v, 0.f);
        C[(size_t)row*N + col] = f2b(v);
      }
    }
  }
}

// ---------------- fused 2-layer encoder recurrence, pipelined ----------------
// 256 WGs x 64 thr. Stage 0 (wid<128): layer 0 at t=r. Stage 1: layer 1 at
// t=r-1, gi computed on the fly from h0[t]. 513 rounds, one monotone counter
// per round (8 cacheline-split subs, target 256). All h traffic = relaxed
// agent-scope atomics (L2-bypass). h1seq aliases the dead prefix of gi.
__device__ __forceinline__ void spinwait(int* cnt, int r){
  for (;;){
    int s = 0;
    #pragma unroll
    for (int i = 0; i < 8; i++)
      s += __hip_atomic_load(&cnt[i*(TT+1) + r], __ATOMIC_RELAXED, __HIP_MEMORY_SCOPE_AGENT);
    if (s == NARRIVE) break;
    __builtin_amdgcn_s_sleep(1);
  }
  asm volatile("" ::: "memory");
}

__global__ __launch_bounds__(64) void enc_fused(
    const u16* gi,        // [TT*32,3072] layer-0 gi (bih0 incl)
    const u16* wih1,      // [3072,1024]
    const u16* whh0, const u16* whh1,
    const u16* bih1, const u16* bhh0, const u16* bhh1,
    u16* h0seq,           // [TT*32,1024]
    u16* h1seq,           // [TT*32,1024] compact, aliases gi prefix (safe)
    int* cnt)
{
  const int wid = blockIdx.x;
  const int stage = wid >> 7;
  const int wid2 = wid & 127;
  const int lane = threadIdx.x & 63;
  const int q = lane >> 4, lr = lane & 15;
  const int jg = wid2 >> 1, bh = wid2 & 1;
  const int j = jg*16 + lr;
  const int bbase = bh*16;
  const int sub = wid & 7;
  float hreg[4] = {0.f,0.f,0.f,0.f};

  if (stage == 0){
    const float bh_r = b2f(bhh0[j]);
    const float bh_z = b2f(bhh0[H8 + j]);
    const float bh_n = b2f(bhh0[2*H8 + j]);
    const u16* wp0 = whh0 + (size_t)(0*H8 + j)*H8 + q*8;
    const u16* wp1 = whh0 + (size_t)(1*H8 + j)*H8 + q*8;
    const u16* wp2 = whh0 + (size_t)(2*H8 + j)*H8 + q*8;
    u16 gpre[12];
    #pragma unroll
    for (int r = 0; r < 4; r++){
      size_t row = (size_t)(bbase + q*4 + r)*H3;
      gpre[r]   = gi[row + j];
      gpre[4+r] = gi[row + H8 + j];
      gpre[8+r] = gi[row + 2*H8 + j];
    }
    for (int rd = 0; rd <= TT; rd++){
      if (rd > 0) spinwait(cnt, rd - 1);
      if (rd < TT){
        const int t = rd;
        float gr_[4], gz_[4], gn_[4];
        #pragma unroll
        for (int r = 0; r < 4; r++){
          gr_[r] = b2f(gpre[r]); gz_[r] = b2f(gpre[4+r]); gn_[r] = b2f(gpre[8+r]);
        }
        f32x4 acc0 = {}, acc1 = {}, acc2 = {};
        if (t > 0){
          const u16* ap = h0seq + (size_t)((t-1)*BSZ + bbase + lr)*H8 + q*8;
          #pragma unroll 8
          for (int kb = 0; kb < 32; kb++){
            const u64* p = (const u64*)(ap + kb*32);
            union { u64 v[2]; bf16x8 b; } A; A.v[0] = aload64(p); A.v[1] = aload64(p+1);
            bf16x8 w0 = *(const bf16x8*)(wp0 + kb*32);
            bf16x8 w1 = *(const bf16x8*)(wp1 + kb*32);
            bf16x8 w2 = *(const bf16x8*)(wp2 + kb*32);
            acc0 = __builtin_amdgcn_mfma_f32_16x16x32_bf16(A.b, w0, acc0, 0,0,0);
            acc1 = __builtin_amdgcn_mfma_f32_16x16x32_bf16(A.b, w1, acc1, 0,0,0);
            acc2 = __builtin_amdgcn_mfma_f32_16x16x32_bf16(A.b, w2, acc2, 0,0,0);
          }
        }
        #pragma unroll
        for (int r = 0; r < 4; r++){
          float rr = sigm(gr_[r] + acc0[r] + bh_r);
          float zz = sigm(gz_[r] + acc1[r] + bh_z);
          float nn = tanh_f(gn_[r] + rr*(acc2[r] + bh_n));
          float hnew = (1.f - zz)*nn + zz*hreg[r];
          hreg[r] = hnew;
          __hip_atomic_store(&h0seq[(size_t)(t*BSZ + bbase + q*4 + r)*H8 + j], f2b(hnew),
                             __ATOMIC_RELAXED, __HIP_MEMORY_SCOPE_AGENT);
        }
      }
      asm volatile("s_waitcnt vmcnt(0)" ::: "memory");
      if (lane == 0)
        __hip_atomic_fetch_add(&cnt[sub*(TT+1) + rd], 1, __ATOMIC_RELAXED, __HIP_MEMORY_SCOPE_AGENT);
      if (rd + 1 < TT){
        #pragma unroll
        for (int r = 0; r < 4; r++){
          size_t row = (size_t)((rd+1)*BSZ + bbase + q*4 + r)*H3;
          gpre[r]   = gi[row + j];
          gpre[4+r] = gi[row + H8 + j];
          gpre[8+r] = gi[row + 2*H8 + j];
        }
      }
    }
  } else {
    const float bir = b2f(bih1[j]);
    const float biz = b2f(bih1[H8 + j]);
    const float bin = b2f(bih1[2*H8 + j]);
    const float bhr = b2f(bhh1[j]);
    const float bhz = b2f(bhh1[H8 + j]);
    const float bhn = b2f(bhh1[2*H8 + j]);
    const u16* ip0 = wih1 + (size_t)(0*H8 + j)*H8 + q*8;
    const u16* ip1 = wih1 + (size_t)(1*H8 + j)*H8 + q*8;
    const u16* ip2 = wih1 + (size_t)(2*H8 + j)*H8 + q*8;
    const u16* hp0 = whh1 + (size_t)(0*H8 + j)*H8 + q*8;
    const u16* hp1 = whh1 + (size_t)(1*H8 + j)*H8 + q*8;
    const u16* hp2 = whh1 + (size_t)(2*H8 + j)*H8 + q*8;
    for (int rd = 0; rd <= TT; rd++){
      if (rd > 0) spinwait(cnt, rd - 1);
      if (rd >= 1){
        const int t = rd - 1;
        f32x4 aI0 = {}, aI1 = {}, aI2 = {}, aH0 = {}, aH1 = {}, aH2 = {};
        const u16* a0p = h0seq + (size_t)(t*BSZ + bbase + lr)*H8 + q*8;
        if (t > 0){
          const u16* a1p = h1seq + (size_t)((t-1)*BSZ + bbase + lr)*H8 + q*8;
          #pragma unroll 4
          for (int kb = 0; kb < 32; kb++){
            const u64* p0 = (const u64*)(a0p + kb*32);
            union { u64 v[2]; bf16x8 b; } A0; A0.v[0] = aload64(p0); A0.v[1] = aload64(p0+1);
            const u64* p1 = (const u64*)(a1p + kb*32);
            union { u64 v[2]; bf16x8 b; } A1; A1.v[0] = aload64(p1); A1.v[1] = aload64(p1+1);
            bf16x8 i0 = *(const bf16x8*)(ip0 + kb*32);
            bf16x8 i1 = *(const bf16x8*)(ip1 + kb*32);
            bf16x8 i2 = *(const bf16x8*)(ip2 + kb*32);
            bf16x8 h0v = *(const bf16x8*)(hp0 + kb*32);
            bf16x8 h1v = *(const bf16x8*)(hp1 + kb*32);
            bf16x8 h2v = *(const bf16x8*)(hp2 + kb*32);
            aI0 = __builtin_amdgcn_mfma_f32_16x16x32_bf16(A0.b, i0, aI0, 0,0,0);
            aI1 = __builtin_amdgcn_mfma_f32_16x16x32_bf16(A0.b, i1, aI1, 0,0,0);
            aI2 = __builtin_amdgcn_mfma_f32_16x16x32_bf16(A0.b, i2, aI2, 0,0,0);
            aH0 = __builtin_amdgcn_mfma_f32_16x16x32_bf16(A1.b, h0v, aH0, 0,0,0);
            aH1 = __builtin_amdgcn_mfma_f32_16x16x32_bf16(A1.b, h1v, aH1, 0,0,0);
            aH2 = __builtin_amdgcn_mfma_f32_16x16x32_bf16(A1.b, h2v, aH2, 0,0,0);
          }
        } else {
          #pragma unroll 8
          for (int kb = 0; kb < 32; kb++){
            const u64* p0 = (const u64*)(a0p + kb*32);
            union { u64 v[2]; bf16x8 b; } A0; A0.v[0] = aload64(p0); A0.v[1] = aload64(p0+1);
            bf16x8 i0 = *(const bf16x8*)(ip0 + kb*32);
            bf16x8 i1 = *(const bf16x8*)(ip1 + kb*32);
            bf16x8 i2 = *(const bf16x8*)(ip2 + kb*32);
            aI0 = __builtin_amdgcn_mfma_f32_16x16x32_bf16(A0.b, i0, aI0, 0,0,0);
            aI1 = __builtin_amdgcn_mfma_f32_16x16x32_bf16(A0.b, i1, aI1, 0,0,0);
            aI2 = __builtin_amdgcn_mfma_f32_16x16x32_bf16(A0.b, i2, aI2, 0,0,0);
          }
        }
        #pragma unroll
        for (int r = 0; r < 4; r++){
          float rr = sigm(aI0[r] + bir + aH0[r] + bhr);
          float zz = sigm(aI1[r] + biz + aH1[r] + bhz);
          float nn = tanh_f(aI2[r] + bin + rr*(aH2[r] + bhn));
          float hnew = (1.f - zz)*nn + zz*hreg[r];
          hreg[r] = hnew;
          __hip_atomic_store(&h1seq[(size_t)(t*BSZ + bbase + q*4 + r)*H8 + j], f2b(hnew),
                             __ATOMIC_RELAXED, __HIP_MEMORY_SCOPE_AGENT);
        }
      }
      asm volatile("s_waitcnt vmcnt(0)" ::: "memory");
      if (lane == 0)
        __hip_atomic_fetch_add(&cnt[sub*(TT+1) + rd], 1, __ATOMIC_RELAXED, __HIP_MEMORY_SCOPE_AGENT);
    }
  }
}

// ---------------- fused decoder: dec0 + dec1 (gi on the fly) + final linear ----
// 2 WGs x 512 thr (WG = 16 batches). Waves 0-3: dec0 at t=r (gi0 from LDS,
// staged via coalesced 16B loads). Waves 4-7: dec1 at t=r-1 + final at t=r-2.
// LDS parity buffers; one __syncthreads per round; 514 rounds.
__global__ __launch_bounds__(512) void dec_fused(
    const u16* __restrict__ gi0,   // [TT*32,384] (bih0 incl)
    const u16* __restrict__ whh0, const u16* __restrict__ bhh0,
    const u16* __restrict__ wih1, const u16* __restrict__ whh1,
    const u16* __restrict__ bih1, const u16* __restrict__ bhh1,
    const u16* __restrict__ dlwT, const u16* __restrict__ dlb,
    void* __restrict__ out, const int* __restrict__ flag)
{
  __shared__ u16 h3[2][16*136];
  __shared__ u16 h4[2][16*136];
  __shared__ u16 gib[2][6144];
  const int bb = blockIdx.x*16;
  const int tid = threadIdx.x;
  const int wv = tid >> 6, lane = tid & 63, q = lane >> 4, lr = lane & 15;
  const int stage = wv >> 2, w = wv & 3;
  const int of32 = *flag;
  float hreg[2][4] = {};
  float b0[3][2], bi1[3][2], bh1[3][2], bl[2];
  bf16x8 lw[2][4];
  #pragma unroll
  for (int g2 = 0; g2 < 3; g2++)
    #pragma unroll
    for (int nt = 0; nt < 2; nt++){
      int jj = g2*128 + w*32 + nt*16 + lr;
      if (stage == 0) b0[g2][nt] = b2f(bhh0[jj]);
      else { bi1[g2][nt] = b2f(bih1[jj]); bh1[g2][nt] = b2f(bhh1[jj]); }
    }
  if (stage == 1){
    #pragma unroll
    for (int nt = 0; nt < 2; nt++){
      int jj = w*32 + nt*16 + lr;
      bl[nt] = b2f(dlb[jj]);
      #pragma unroll
      for (int kb = 0; kb < 4; kb++)
        lw[nt][kb] = *(const bf16x8*)(dlwT + (size_t)jj*128 + kb*32 + q*8);
    }
  }
  // pre-stage gi for t=0 into gib[0]
  {
    const u16* gb = gi0 + (size_t)bb*384;
    bf16x8 g0 = *(const bf16x8*)(gb + tid*8);
    *(bf16x8*)(gib[0] + tid*8) = g0;
    if (tid < 256){
      bf16x8 g1 = *(const bf16x8*)(gb + (512+tid)*8);
      *(bf16x8*)(gib[0] + (512+tid)*8) = g1;
    }
  }
  for (int rd = 0; rd < TT+2; rd++){
    __syncthreads();
    // issue next-step gi loads (coalesced 16B)
    bf16x8 g0, g1;
    const int stg = (rd + 1 < TT);
    if (stg){
      const u16* gb = gi0 + (size_t)((rd+1)*BSZ + bb)*384;
      g0 = *(const bf16x8*)(gb + tid*8);
      if (tid < 256) g1 = *(const bf16x8*)(gb + (512+tid)*8);
    }
    if (stage == 0){
      if (rd < TT){
        float gif[3][2][4];
        #pragma unroll
        for (int r = 0; r < 4; r++){
          int base = (q*4 + r)*384;
          #pragma unroll
          for (int g2 = 0; g2 < 3; g2++)
            #pragma unroll
            for (int nt = 0; nt < 2; nt++)
              gif[g2][nt][r] = b2f(gib[rd&1][base + g2*128 + w*32 + nt*16 + lr]);
        }
        f32x4 accH[3][2] = {};
        if (rd > 0){
          #pragma unroll
          for (int kb = 0; kb < 4; kb++){
            bf16x8 a = *(const bf16x8*)(&h3[(rd-1)&1][lr*136 + kb*32 + q*8]);
            #pragma unroll
            for (int g2 = 0; g2 < 3; g2++)
              #pragma unroll
              for (int nt = 0; nt < 2; nt++){
                bf16x8 bw = *(const bf16x8*)(whh0 + (size_t)(g2*128 + w*32 + nt*16 + lr)*128 + kb*32 + q*8);
                accH[g2][nt] = __builtin_amdgcn_mfma_f32_16x16x32_bf16(a, bw, accH[g2][nt], 0,0,0);
              }
          }
        }
        #pragma unroll
        for (int nt = 0; nt < 2; nt++)
          #pragma unroll
          for (int r = 0; r < 4; r++){
            float rr = sigm(gif[0][nt][r] + accH[0][nt][r] + b0[0][nt]);
            float zz = sigm(gif[1][nt][r] + accH[1][nt][r] + b0[1][nt]);
            float nn = tanh_f(gif[2][nt][r] + rr*(accH[2][nt][r] + b0[2][nt]));
            float hnew = (1.f - zz)*nn + zz*hreg[nt][r];
            hreg[nt][r] = hnew;
            h3[rd&1][(q*4 + r)*136 + w*32 + nt*16 + lr] = f2b(hnew);
          }
      }
    } else {
      if (rd >= 1 && rd <= TT){
        const int t1 = rd - 1;
        f32x4 accI[3][2] = {}, accH[3][2] = {};
        #pragma unroll
        for (int kb = 0; kb < 4; kb++){
          bf16x8 a0 = *(const bf16x8*)(&h3[(rd-1)&1][lr*136 + kb*32 + q*8]);
          #pragma unroll
          for (int g2 = 0; g2 < 3; g2++)
            #pragma unroll
            for (int nt = 0; nt < 2; nt++){
              bf16x8 bw = *(const bf16x8*)(wih1 + (size_t)(g2*128 + w*32 + nt*16 + lr)*128 + kb*32 + q*8);
              accI[g2][nt] = __builtin_amdgcn_mfma_f32_16x16x32_bf16(a0, bw, accI[g2][nt], 0,0,0);
            }
        }
        if (t1 > 0){
          #pragma unroll
          for (int kb = 0; kb < 4; kb++){
            bf16x8 a1 = *(const bf16x8*)(&h4[(rd-2)&1][lr*136 + kb*32 + q*8]);
            #pragma unroll
            for (int g2 = 0; g2 < 3; g2++)
              #pragma unroll
              for (int nt = 0; nt < 2; nt++){
                bf16x8 bw = *(const bf16x8*)(whh1 + (size_t)(g2*128 + w*32 + nt*16 + lr)*128 + kb*32 + q*8);
                accH[g2][nt] = __builtin_amdgcn_mfma_f32_16x16x32_bf16(a1, bw, accH[g2][nt], 0,0,0);
              }
          }
        }
        #pragma unroll
        for (int nt = 0; nt < 2; nt++)
          #pragma unroll
          for (int r = 0; r < 4; r++){
            float rr = sigm(accI[0][nt][r] + bi1[0][nt] + accH[0][nt][r] + bh1[0][nt]);
            float zz = sigm(accI[1][nt][r] + bi1[1][nt] + accH[1][nt][r] + bh1[1][nt]);
            float nn = tanh_f(accI[2][nt][r] + bi1[2][nt] + rr*(accH[2][nt][r] + bh1[2][nt]));
            float hnew = (1.f - zz)*nn + zz*hreg[nt][r];
            hreg[nt][r] = hnew;
            h4[(rd-1)&1][(q*4 + r)*136 + w*32 + nt*16 + lr] = f2b(hnew);
          }
      }
      if (rd >= 2){
        const int tf = rd - 2;
        f32x4 accF[2] = {};
        #pragma unroll
        for (int kb = 0; kb < 4; kb++){
          bf16x8 a = *(const bf16x8*)(&h4[(rd-2)&1][lr*136 + kb*32 + q*8]);
          #pragma unroll
          for (int nt = 0; nt < 2; nt++)
            accF[nt] = __builtin_amdgcn_mfma_f32_16x16x32_bf16(a, lw[nt][kb], accF[nt], 0,0,0);
        }
        #pragma unroll
        for (int nt = 0; nt < 2; nt++)
          #pragma unroll
          for (int r = 0; r < 4; r++){
            float v = accF[nt][r] + bl[nt];
            int b = bb + q*4 + r;
            size_t idx = (size_t)(b*TT + tf)*128 + w*32 + nt*16 + lr;
            if (of32) ((float*)out)[idx] = v;
            else      ((u16*)out)[idx]   = f2b(v);
          }
      }
    }
    if (stg){
      *(bf16x8*)(gib[(rd+1)&1] + tid*8) = g0;
      if (tid < 256) *(bf16x8*)(gib[(rd+1)&1] + (512+tid)*8) = g1;
    }
  }
}

extern "C" void kernel_launch(void* const* d_in, const int* in_sizes, int n_in,
                              void* d_out, int out_size, void* d_ws, size_t ws_size,
                              hipStream_t stream)
{
  const void* x    = d_in[0];
  const int* ei    = (const int*)d_in[1];

  const size_t NEED = (size_t)164 << 20;
  if (ws_size < NEED) return;
  char* wsb = (char*)d_ws;
  const size_t KB = 1024, MB = 1024*1024;

  int* syncv = (int*)wsb;                       // 32 KB counters
  int* flag  = (int*)(wsb + 40*KB);
  u16* gw1_c  = (u16*)(wsb + 1*MB + 0);
  u16* gb1_c  = (u16*)(wsb + 1*MB + 64);
  u16* gw2_c  = (u16*)(wsb + 1*MB + 128);
  u16* gb2_c  = (u16*)(wsb + 1*MB + 192);
  u16* gcw_c  = (u16*)(wsb + 1*MB + 256);
  u16* gcb_c  = (u16*)(wsb + 1*MB + 320);
  u16* efb_c  = (u16*)(wsb + 1*MB + 4*KB);
  u16* ebih_c = (u16*)(wsb + 1*MB + 8*KB);
  u16* ebhh_c = (u16*)(wsb + 1*MB + 24*KB);
  u16* dfb_c  = (u16*)(wsb + 1*MB + 40*KB);
  u16* dbih_c = (u16*)(wsb + 1*MB + 45*KB);
  u16* dbhh_c = (u16*)(wsb + 1*MB + 47*KB);
  u16* dlb_c  = (u16*)(wsb + 1*MB + 49*KB);
  u16* wT3    = (u16*)(wsb + 1*MB + 64*KB);
  u16* dlw_c  = (u16*)(wsb + 1*MB + 128*KB);
  u16* efw_c  = (u16*)(wsb + 1*MB + 192*KB);
  u16* wT1    = (u16*)(wsb + 1*MB + 448*KB);
  u16* dfw_c  = (u16*)(wsb + 2*MB);
  u16* wT2    = (u16*)(wsb + 4*MB);
  u16* dwih0_c= (u16*)(wsb + 6*MB);
  u16* dwih1_c= (u16*)(wsb + 7*MB);
  u16* dwhh_c = (u16*)(wsb + 7*MB + 128*KB);
  u16* ewih_c = (u16*)(wsb + 8*MB);
  u16* ewhh_c = (u16*)(wsb + 20*MB);
  u16* res    = (u16*)(wsb + 32*MB);            // 4MB  [GG,128] GCN out
  u16* bufA   = (u16*)(wsb + 36*MB);            // 32MB x0 -> h0seq -> giD0
  u16* bufC   = (u16*)(wsb + 68*MB);            // 96MB gi0; h1seq prefix; d0 at +32MB
  u16* x_c    = bufC;                           // 4MB alias (dead before gi0)
  u16* h1seq  = bufC;                           // compact [TT*32,1024] in dead prefix
  u16* d0     = (u16*)(wsb + 100*MB);           // 32MB [TT*32,1024]
  u16* giD0   = bufA;                           // 12MB [TT*32,384]

  hipMemsetAsync(syncv, 0, 32*KB, stream);
  detect_dtype<<<1, 256, 0, stream>>>(x, flag);

  auto cvt = [&](int idx, u16* dst, int n){
    cvt_bf16<<<(n + 255)/256, 256, 0, stream>>>(d_in[idx], dst, n, flag);
  };
  cvt(0,  x_c,     GG*NNODE*2);
  cvt(2,  gw1_c, 8);  cvt(3, gb1_c, 4);  cvt(4, gw2_c, 8);
  cvt(5,  gb2_c, 2);  cvt(6, gcw_c, 4);  cvt(7, gcb_c, 2);
  cvt(8,  efw_c,   128*1024);   cvt(9,  efb_c, 1024);
  cvt(10, ewih_c,  2*3072*1024);
  cvt(11, ewhh_c,  2*3072*1024);
  cvt(12, ebih_c,  2*3072);     cvt(13, ebhh_c, 2*3072);
  cvt(14, dfw_c,   1024*1024);  cvt(15, dfb_c, 1024);
  cvt(16, dwih0_c, 384*1024);   cvt(17, dwih1_c, 384*128);
  cvt(18, dwhh_c,  2*384*128);
  cvt(19, dbih_c,  2*384);      cvt(20, dbhh_c, 2*384);
  cvt(21, dlw_c,   128*128);    cvt(22, dlb_c, 128);

  transpose_bf16<<<dim3(1024/32, 128/32),  dim3(32,8), 0, stream>>>(efw_c, wT1, 128, 1024);
  transpose_bf16<<<dim3(1024/32, 1024/32), dim3(32,8), 0, stream>>>(dfw_c, wT2, 1024, 1024);
  transpose_bf16<<<dim3(128/32, 128/32),   dim3(32,8), 0, stream>>>(dlw_c, wT3, 128, 128);

  // GCN -> res [GG,128] (b-major)
  gcn_kernel<<<GG, 64, 0, stream>>>(x_c, ei, gw1_c, gb1_c, gw2_c, gb2_c, gcw_c, gcb_c, res);

  // encoder fl: x0 = relu(res @ efw + efb) -> bufA [t][b]
  gemm_nt<<<dim3(1024/128, GG/128), 256, 0, stream>>>(res, wT1, efb_c, bufA, GG, 1024, 128, 1, 0, 1);
  // enc layer-0 gi: x0 @ ewih0 -> bufC [t][b][3072]
  gemm_nt<<<dim3(3072/128, GG/128), 256, 0, stream>>>(bufA, ewih_c, ebih_c, bufC, GG, 3072, 1024, 0, 1, 1);
  // fused 2-layer encoder recurrence: h0 -> bufA, h1(seq2) -> h1seq (bufC prefix)
  enc_fused<<<256, 64, 0, stream>>>(bufC, ewih_c + 3072*1024, ewhh_c, ewhh_c + 3072*1024,
                                    ebih_c + 3072, ebhh_c, ebhh_c + 3072,
                                    bufA, h1seq, syncv);

  // decoder fl: d0 = relu(seq2 @ dfw + dfb) -> d0 [t][b]
  gemm_nt<<<dim3(1024/128, GG/128), 256, 0, stream>>>(h1seq, wT2, dfb_c, d0, GG, 1024, 1024, 1, 1, 1);
  // dec layer-0 gi: d0 @ dwih0 -> giD0 (bufA) [t][b][384]
  gemm_nt<<<dim3(384/128, GG/128), 256, 0, stream>>>(d0, dwih0_c, dbih_c, giD0, GG, 384, 1024, 0, 1, 1);
  // fused decoder (dec0 + dec1 + final linear) -> d_out
  dec_fused<<<2, 512, 0, stream>>>(giD0, dwhh_c, dbhh_c, dwih1_c, dwhh_c + 384*128,
                                   dbih_c + 384, dbhh_c + 384, wT3, dlb_c, d_out, flag);
}